// Round 1
// baseline (254.790 us; speedup 1.0000x reference)
//
#include <hip/hip_runtime.h>
#include <cmath>

// Problem constants (B,N,D,H fixed by the reference)
#define BB 4
#define NN 1024
#define DD 512
#define HH 8
#define HDIM 64
#define ROWS (BB * NN)   // 4096
#define NCHUNK 16        // chunks of 64 along N per (b,h)

// ---------------------------------------------------------------------------
// Tiled fp32 GEMM: out_tile(64x64) = X(64x512) @ W^T(512x64) + bias
// MODE 0: elu + per-row L2-normalize (over the 64-wide head), write (B,H,N,64)
// MODE 1: plain, write (B,H,N,64)
// MODE 2: plain, write row-major (ROWS x 512)
// ---------------------------------------------------------------------------
template<int MODE>
__global__ __launch_bounds__(256)
void proj_gemm(const float* __restrict__ X, const float* __restrict__ W,
               const float* __restrict__ bias, float* __restrict__ out)
{
    __shared__ float Xs[32][65];    // [kk][row], pad -> conflict-free
    __shared__ float Ws[32][65];    // [kk][col]
    __shared__ float red[64][17];
    __shared__ float scale[64];

    const int r0 = blockIdx.x * 64;
    const int c0 = blockIdx.y * 64;
    const int t  = threadIdx.x;
    const int ty = t >> 4;
    const int tx = t & 15;

    float acc[4][4] = {};

    for (int k0 = 0; k0 < DD; k0 += 32) {
        #pragma unroll
        for (int i = 0; i < 8; ++i) {
            int f   = t + i * 256;          // 0..2047
            int row = f >> 5;
            int kk  = f & 31;
            Xs[kk][row] = X[(size_t)(r0 + row) * DD + k0 + kk];
            Ws[kk][row] = W[(size_t)(c0 + row) * DD + k0 + kk];
        }
        __syncthreads();
        #pragma unroll
        for (int kk = 0; kk < 32; ++kk) {
            float xv[4], wv[4];
            #pragma unroll
            for (int i = 0; i < 4; ++i) xv[i] = Xs[kk][ty * 4 + i];
            #pragma unroll
            for (int j = 0; j < 4; ++j) wv[j] = Ws[kk][tx * 4 + j];
            #pragma unroll
            for (int i = 0; i < 4; ++i)
                #pragma unroll
                for (int j = 0; j < 4; ++j)
                    acc[i][j] += xv[i] * wv[j];
        }
        __syncthreads();
    }

    // bias
    #pragma unroll
    for (int j = 0; j < 4; ++j) {
        float bv = bias[c0 + tx * 4 + j];
        #pragma unroll
        for (int i = 0; i < 4; ++i) acc[i][j] += bv;
    }

    if (MODE == 0) {
        // elu
        #pragma unroll
        for (int i = 0; i < 4; ++i)
            #pragma unroll
            for (int j = 0; j < 4; ++j) {
                float v = acc[i][j];
                acc[i][j] = (v > 0.f) ? v : (expf(v) - 1.f);
            }
        // per-row L2 norm across the tile's 64 cols (== one head)
        #pragma unroll
        for (int i = 0; i < 4; ++i) {
            float ss = 0.f;
            #pragma unroll
            for (int j = 0; j < 4; ++j) ss += acc[i][j] * acc[i][j];
            red[ty * 4 + i][tx] = ss;
        }
        __syncthreads();
        if (t < 64) {
            float s = 0.f;
            #pragma unroll
            for (int xx = 0; xx < 16; ++xx) s += red[t][xx];
            scale[t] = 1.f / fmaxf(sqrtf(s), 1e-12f);
        }
        __syncthreads();
        #pragma unroll
        for (int i = 0; i < 4; ++i) {
            float sc = scale[ty * 4 + i];
            #pragma unroll
            for (int j = 0; j < 4; ++j) acc[i][j] *= sc;
        }
    }

    if (MODE <= 1) {
        const int h = blockIdx.y;
        #pragma unroll
        for (int i = 0; i < 4; ++i) {
            int r = r0 + ty * 4 + i;
            int b = r >> 10;           // N = 1024
            int n = r & 1023;
            float* dst = out + (((size_t)(b * HH + h)) * NN + n) * HDIM;
            #pragma unroll
            for (int j = 0; j < 4; ++j) dst[tx * 4 + j] = acc[i][j];
        }
    } else {
        #pragma unroll
        for (int i = 0; i < 4; ++i) {
            int r = r0 + ty * 4 + i;
            #pragma unroll
            for (int j = 0; j < 4; ++j)
                out[(size_t)r * DD + c0 + tx * 4 + j] = acc[i][j];
        }
    }
}

// ---------------------------------------------------------------------------
// Per-chunk state: S_c[d][e] = sum_{n in chunk} K[n][d] * V[n][e]   (64x64)
// ---------------------------------------------------------------------------
__global__ __launch_bounds__(256)
void chunk_state(const float* __restrict__ kb, const float* __restrict__ vb,
                 float* __restrict__ S)
{
    __shared__ float Ks[64 * 64];
    __shared__ float Vs[64 * 64];

    const int bh = blockIdx.x;   // 0..31
    const int c  = blockIdx.y;   // 0..15
    const int t  = threadIdx.x;

    const float* kg = kb + ((size_t)bh * NN + c * 64) * HDIM;
    const float* vg = vb + ((size_t)bh * NN + c * 64) * HDIM;

    #pragma unroll
    for (int i = 0; i < 16; ++i) {
        Ks[t + i * 256] = kg[t + i * 256];
        Vs[t + i * 256] = vg[t + i * 256];
    }
    __syncthreads();

    const int d  = t >> 2;
    const int e0 = (t & 3) * 16;
    float acc[16] = {};
    for (int n = 0; n < 64; ++n) {
        float kv = Ks[n * 64 + d];
        #pragma unroll
        for (int j = 0; j < 16; ++j) acc[j] += kv * Vs[n * 64 + e0 + j];
    }
    float* sg = S + ((size_t)bh * NCHUNK + c) * 4096;
    #pragma unroll
    for (int j = 0; j < 16; ++j) sg[d * 64 + e0 + j] = acc[j];
}

// ---------------------------------------------------------------------------
// In-place exclusive prefix over the 16 chunk states per (b,h)
// ---------------------------------------------------------------------------
__global__ __launch_bounds__(256)
void prefix_scan(float* __restrict__ S)
{
    const int bh = blockIdx.x;
    float* sg = S + (size_t)bh * NCHUNK * 4096;
    for (int idx = threadIdx.x; idx < 4096; idx += 256) {
        float run = 0.f;
        #pragma unroll
        for (int c = 0; c < NCHUNK; ++c) {
            float v = sg[c * 4096 + idx];
            sg[c * 4096 + idx] = run;
            run += v;
        }
    }
}

// ---------------------------------------------------------------------------
// Chunk attention: O = Q @ P + tril(Q K^T) @ V, write to row-major attn buf
// ---------------------------------------------------------------------------
__global__ __launch_bounds__(256)
void attn_chunk(const float* __restrict__ qb, const float* __restrict__ kb,
                const float* __restrict__ vb, const float* __restrict__ S,
                float* __restrict__ attn)
{
    __shared__ float Qs[64][65];   // [i][d]
    __shared__ float Kt[64][65];   // [d][j]  (transposed K)
    __shared__ float Vs[64 * 64];  // [j][e]
    __shared__ float Ps[64 * 64];  // [d][e]
    __shared__ float As[64][65];   // [i][j], zero above diagonal

    const int bh = blockIdx.x;   // b*8+h
    const int c  = blockIdx.y;
    const int t  = threadIdx.x;

    const float* qg = qb + ((size_t)bh * NN + c * 64) * HDIM;
    const float* kg = kb + ((size_t)bh * NN + c * 64) * HDIM;
    const float* vg = vb + ((size_t)bh * NN + c * 64) * HDIM;
    const float* sg = S + ((size_t)bh * NCHUNK + c) * 4096;

    #pragma unroll
    for (int i = 0; i < 16; ++i) {
        int f = t + i * 256;
        int n = f >> 6;
        int d = f & 63;
        Qs[n][d] = qg[f];
        Kt[d][n] = kg[f];
        Vs[f]    = vg[f];
        Ps[f]    = sg[f];
    }
    __syncthreads();

    const int i  = t >> 2;
    const int j0 = (t & 3) * 16;

    // scores A[i][j] = q_i . k_j (masked j<=i)
    float a[16] = {};
    for (int d = 0; d < 64; ++d) {
        float qv = Qs[i][d];
        #pragma unroll
        for (int jj = 0; jj < 16; ++jj) a[jj] += qv * Kt[d][j0 + jj];
    }
    #pragma unroll
    for (int jj = 0; jj < 16; ++jj)
        As[i][j0 + jj] = (j0 + jj <= i) ? a[jj] : 0.f;
    __syncthreads();

    // o[i][e] = sum_d Q[i][d]*P[d][e] + sum_j A[i][j]*V[j][e]
    float o[16] = {};
    for (int d = 0; d < 64; ++d) {
        float qv = Qs[i][d];
        #pragma unroll
        for (int jj = 0; jj < 16; ++jj) o[jj] += qv * Ps[d * 64 + j0 + jj];
    }
    for (int j = 0; j < 64; ++j) {
        float av = As[i][j];
        #pragma unroll
        for (int jj = 0; jj < 16; ++jj) o[jj] += av * Vs[j * 64 + j0 + jj];
    }

    const int b = bh >> 3;
    const int h = bh & 7;
    const int n = c * 64 + i;
    float* dst = attn + ((size_t)b * NN + n) * DD + h * HDIM;
    #pragma unroll
    for (int jj = 0; jj < 16; ++jj) dst[j0 + jj] = o[jj];
}

// ---------------------------------------------------------------------------
extern "C" void kernel_launch(void* const* d_in, const int* in_sizes, int n_in,
                              void* d_out, int out_size, void* d_ws, size_t ws_size,
                              hipStream_t stream)
{
    (void)in_sizes; (void)n_in; (void)out_size; (void)ws_size;

    const float* x  = (const float*)d_in[0];
    const float* Wq = (const float*)d_in[1];
    const float* Wk = (const float*)d_in[2];
    const float* Wv = (const float*)d_in[3];
    const float* Wo = (const float*)d_in[4];
    const float* bq = (const float*)d_in[5];
    const float* bk = (const float*)d_in[6];
    const float* bv = (const float*)d_in[7];
    const float* bo = (const float*)d_in[8];
    float* out = (float*)d_out;

    float* ws   = (float*)d_ws;
    const size_t PLANE = (size_t)ROWS * DD;      // 2M floats
    float* qb   = ws;
    float* kb   = ws + PLANE;
    float* vb   = ws + 2 * PLANE;
    float* attn = ws + 3 * PLANE;
    float* st   = ws + 4 * PLANE;                // 32*16*4096 = 2M floats

    dim3 blk(256);
    dim3 gp(ROWS / 64, HH);

    proj_gemm<0><<<gp, blk, 0, stream>>>(x, Wq, bq, qb);
    proj_gemm<0><<<gp, blk, 0, stream>>>(x, Wk, bk, kb);
    proj_gemm<1><<<gp, blk, 0, stream>>>(x, Wv, bv, vb);

    chunk_state<<<dim3(32, NCHUNK), blk, 0, stream>>>(kb, vb, st);
    prefix_scan<<<dim3(32), blk, 0, stream>>>(st);
    attn_chunk<<<dim3(32, NCHUNK), blk, 0, stream>>>(qb, kb, vb, st, attn);

    proj_gemm<2><<<gp, blk, 0, stream>>>(attn, Wo, bo, out);
}

// Round 2
// 149.892 us; speedup vs baseline: 1.6998x; 1.6998x over previous
//
#include <hip/hip_runtime.h>
#include <cmath>

// Problem constants
#define BB 4
#define NN 1024
#define DD 512
#define HH 8
#define HDIM 64
#define ROWS (BB * NN)      // 4096
#define NCHUNK 16
#define KAUG 1536           // split-bf16 augmented K: [hi | hi | lo] x [hi | lo | hi]
#define WMAT (512 * KAUG)   // one augmented weight matrix, elems

typedef __bf16 bf16;
typedef bf16  bf16x8 __attribute__((ext_vector_type(8)));
typedef bf16  bf16x4 __attribute__((ext_vector_type(4)));
typedef float f32x4  __attribute__((ext_vector_type(4)));

#define GLOAD_LDS16(g, l) \
    __builtin_amdgcn_global_load_lds((const __attribute__((address_space(1))) void*)(g), \
                                     (__attribute__((address_space(3))) void*)(l), 16, 0, 0)

// ---------------------------------------------------------------------------
// Split fp32 -> augmented bf16 rows: [hi(512) | hi(512) | lo(512)]
// ---------------------------------------------------------------------------
__global__ __launch_bounds__(256)
void split_x(const float* __restrict__ x, bf16* __restrict__ xa)
{
    int t = blockIdx.x * 256 + threadIdx.x;          // 512K threads, 4 elems each
    float4 v = ((const float4*)x)[t];
    float a[4] = {v.x, v.y, v.z, v.w};
    int r = t >> 7;
    int c = (t & 127) * 4;
    bf16x4 hi, lo;
    #pragma unroll
    for (int i = 0; i < 4; ++i) {
        bf16 h = (bf16)a[i];
        hi[i] = h;
        lo[i] = (bf16)(a[i] - (float)h);
    }
    bf16* dst = xa + (size_t)r * KAUG + c;
    *(bf16x4*)(dst)        = hi;
    *(bf16x4*)(dst + 512)  = hi;
    *(bf16x4*)(dst + 1024) = lo;
}

// Weights: [hi(512) | lo(512) | hi(512)]  (pairs with A's [hi|hi|lo])
__global__ __launch_bounds__(256)
void split_w(const float* __restrict__ Wq, const float* __restrict__ Wk,
             const float* __restrict__ Wv, const float* __restrict__ Wo,
             bf16* __restrict__ wa)
{
    int m = blockIdx.y;
    const float* W = (m == 0) ? Wq : (m == 1) ? Wk : (m == 2) ? Wv : Wo;
    int t = blockIdx.x * 256 + threadIdx.x;          // 64K threads per matrix
    float4 v = ((const float4*)W)[t];
    float a[4] = {v.x, v.y, v.z, v.w};
    int r = t >> 7;
    int c = (t & 127) * 4;
    bf16x4 hi, lo;
    #pragma unroll
    for (int i = 0; i < 4; ++i) {
        bf16 h = (bf16)a[i];
        hi[i] = h;
        lo[i] = (bf16)(a[i] - (float)h);
    }
    bf16* dst = wa + (size_t)m * WMAT + (size_t)r * KAUG + c;
    *(bf16x4*)(dst)        = hi;
    *(bf16x4*)(dst + 512)  = lo;
    *(bf16x4*)(dst + 1024) = hi;
}

// ---------------------------------------------------------------------------
// MFMA GEMM: out(4096x512) = A_aug(4096x1536) @ W_aug^T, + bias, + epilogue.
// Tile 128x128, BK=32, 4 waves (each 64x64), 16x16x32 bf16 MFMA.
// OUTMODE 0: grid.z=3 (q,k,v). z<2: elu + per-head L2 norm; write (B,H,N,64) f32.
// OUTMODE 1: plain bias, write row-major f32 (the final output).
// ---------------------------------------------------------------------------
template<int OUTMODE>
__global__ __launch_bounds__(256)
void mm_aug(const bf16* __restrict__ A, const bf16* __restrict__ Wbase,
            const float* __restrict__ b0, const float* __restrict__ b1,
            const float* __restrict__ b2, float* __restrict__ obase)
{
    __shared__ bf16 As[128 * 32];   // [row][k] row-major, 64 B rows
    __shared__ bf16 Bs[128 * 32];   // [col][k]

    const int t    = threadIdx.x;
    const int lane = t & 63;
    const int wid  = t >> 6;
    const int wr   = wid >> 1;          // 0..1
    const int wc   = wid & 1;           // 0..1
    const int l16  = lane & 15;
    const int g16  = lane >> 4;

    const int r0 = blockIdx.x * 128;
    const int c0 = blockIdx.y * 128;
    const int z  = (OUTMODE == 0) ? blockIdx.z : 0;

    const bf16* Wm = Wbase + (size_t)z * WMAT;

    // staging geometry: byte off in 8KB tile = q*4096 + wid*1024 + lane*16
    const int soff = wid * 1024 + lane * 16;
    const int srowA0 = soff >> 6, skbA0 = soff & 63;
    const int srowA1 = (soff + 4096) >> 6, skbA1 = (soff + 4096) & 63;

    f32x4 acc[4][4] = {};

    for (int kt = 0; kt < KAUG / 32; ++kt) {
        const int k0 = kt * 32;
        // stage A (8KB) + B (8KB)
        GLOAD_LDS16(A + (size_t)(r0 + srowA0) * KAUG + k0 + (skbA0 >> 1),
                    As + ((wid * 1024) >> 1));
        GLOAD_LDS16(A + (size_t)(r0 + srowA1) * KAUG + k0 + (skbA1 >> 1),
                    As + ((4096 + wid * 1024) >> 1));
        GLOAD_LDS16(Wm + (size_t)(c0 + srowA0) * KAUG + k0 + (skbA0 >> 1),
                    Bs + ((wid * 1024) >> 1));
        GLOAD_LDS16(Wm + (size_t)(c0 + srowA1) * KAUG + k0 + (skbA1 >> 1),
                    Bs + ((4096 + wid * 1024) >> 1));
        __syncthreads();

        bf16x8 af[4], bfr[4];
        #pragma unroll
        for (int mi = 0; mi < 4; ++mi)
            af[mi] = *(const bf16x8*)((const char*)As + (wr * 64 + mi * 16 + l16) * 64 + g16 * 16);
        #pragma unroll
        for (int ni = 0; ni < 4; ++ni)
            bfr[ni] = *(const bf16x8*)((const char*)Bs + (wc * 64 + ni * 16 + l16) * 64 + g16 * 16);
        #pragma unroll
        for (int mi = 0; mi < 4; ++mi)
            #pragma unroll
            for (int ni = 0; ni < 4; ++ni)
                acc[mi][ni] = __builtin_amdgcn_mfma_f32_16x16x32_bf16(af[mi], bfr[ni], acc[mi][ni], 0, 0, 0);
        __syncthreads();
    }

    if (OUTMODE == 1) {
        #pragma unroll
        for (int mi = 0; mi < 4; ++mi)
            #pragma unroll
            for (int ni = 0; ni < 4; ++ni) {
                int cg = c0 + wc * 64 + ni * 16 + l16;
                float bv = b0[cg];
                #pragma unroll
                for (int r = 0; r < 4; ++r) {
                    int rg = r0 + wr * 64 + mi * 16 + g16 * 4 + r;
                    obase[(size_t)rg * DD + cg] = acc[mi][ni][r] + bv;
                }
            }
    } else {
        const float* bias = (z == 0) ? b0 : (z == 1) ? b1 : b2;
        float* outp = obase + (size_t)z * ((size_t)BB * HH * NN * HDIM);

        // bias (+ elu for q,k)
        #pragma unroll
        for (int mi = 0; mi < 4; ++mi)
            #pragma unroll
            for (int ni = 0; ni < 4; ++ni) {
                float bv = bias[c0 + wc * 64 + ni * 16 + l16];
                #pragma unroll
                for (int r = 0; r < 4; ++r) {
                    float v = acc[mi][ni][r] + bv;
                    if (z < 2) v = (v > 0.f) ? v : expm1f(v);
                    acc[mi][ni][r] = v;
                }
            }
        if (z < 2) {
            // per-(row, head) L2 norm; wave's 64 cols == one head
            #pragma unroll
            for (int mi = 0; mi < 4; ++mi)
                #pragma unroll
                for (int r = 0; r < 4; ++r) {
                    float ss = 0.f;
                    #pragma unroll
                    for (int ni = 0; ni < 4; ++ni) ss += acc[mi][ni][r] * acc[mi][ni][r];
                    ss += __shfl_xor(ss, 1);
                    ss += __shfl_xor(ss, 2);
                    ss += __shfl_xor(ss, 4);
                    ss += __shfl_xor(ss, 8);
                    float sc = 1.f / fmaxf(sqrtf(ss), 1e-12f);
                    #pragma unroll
                    for (int ni = 0; ni < 4; ++ni) acc[mi][ni][r] *= sc;
                }
        }
        const int h = (c0 >> 6) + wc;
        #pragma unroll
        for (int mi = 0; mi < 4; ++mi)
            #pragma unroll
            for (int r = 0; r < 4; ++r) {
                int rg = r0 + wr * 64 + mi * 16 + g16 * 4 + r;
                int b = rg >> 10, n = rg & 1023;
                float* dst = outp + ((size_t)(b * HH + h) * NN + n) * HDIM;
                #pragma unroll
                for (int ni = 0; ni < 4; ++ni) dst[ni * 16 + l16] = acc[mi][ni][r];
            }
    }
}

// ---------------------------------------------------------------------------
// Per-chunk state: S_c[d][e] = sum_{n in chunk} K[n][d] * V[n][e]   (64x64)
// ---------------------------------------------------------------------------
__global__ __launch_bounds__(256)
void chunk_state(const float* __restrict__ kb, const float* __restrict__ vb,
                 float* __restrict__ S)
{
    __shared__ float Ks[64 * 64];
    __shared__ float Vs[64 * 64];

    const int bh = blockIdx.x;
    const int c  = blockIdx.y;
    const int t  = threadIdx.x;

    const float* kg = kb + ((size_t)bh * NN + c * 64) * HDIM;
    const float* vg = vb + ((size_t)bh * NN + c * 64) * HDIM;

    #pragma unroll
    for (int i = 0; i < 16; ++i) {
        Ks[t + i * 256] = kg[t + i * 256];
        Vs[t + i * 256] = vg[t + i * 256];
    }
    __syncthreads();

    const int d  = t >> 2;
    const int e0 = (t & 3) * 16;
    float acc[16] = {};
    for (int n = 0; n < 64; ++n) {
        float kv = Ks[n * 64 + d];
        #pragma unroll
        for (int j = 0; j < 16; ++j) acc[j] += kv * Vs[n * 64 + e0 + j];
    }
    float* sg = S + ((size_t)bh * NCHUNK + c) * 4096;
    #pragma unroll
    for (int j = 0; j < 16; ++j) sg[d * 64 + e0 + j] = acc[j];
}

__global__ __launch_bounds__(256)
void prefix_scan(float* __restrict__ S)
{
    const int bh = blockIdx.x;
    float* sg = S + (size_t)bh * NCHUNK * 4096;
    for (int idx = threadIdx.x; idx < 4096; idx += 256) {
        float run = 0.f;
        #pragma unroll
        for (int c = 0; c < NCHUNK; ++c) {
            float v = sg[c * 4096 + idx];
            sg[c * 4096 + idx] = run;
            run += v;
        }
    }
}

// ---------------------------------------------------------------------------
// Chunk attention: O = Q @ P + tril(Q K^T) @ V  -> write split-bf16 augmented
// rows so the out-projection GEMM consumes them directly.
// ---------------------------------------------------------------------------
__global__ __launch_bounds__(256)
void attn_chunk(const float* __restrict__ qb, const float* __restrict__ kb,
                const float* __restrict__ vb, const float* __restrict__ S,
                bf16* __restrict__ aug)
{
    __shared__ float Qs[64][65];
    __shared__ float Kt[64][65];
    __shared__ float Vs[64 * 64];
    __shared__ float Ps[64 * 64];
    __shared__ float As[64][65];

    const int bh = blockIdx.x;
    const int c  = blockIdx.y;
    const int t  = threadIdx.x;

    const float* qg = qb + ((size_t)bh * NN + c * 64) * HDIM;
    const float* kg = kb + ((size_t)bh * NN + c * 64) * HDIM;
    const float* vg = vb + ((size_t)bh * NN + c * 64) * HDIM;
    const float* sg = S + ((size_t)bh * NCHUNK + c) * 4096;

    #pragma unroll
    for (int i = 0; i < 16; ++i) {
        int f = t + i * 256;
        int n = f >> 6;
        int d = f & 63;
        Qs[n][d] = qg[f];
        Kt[d][n] = kg[f];
        Vs[f]    = vg[f];
        Ps[f]    = sg[f];
    }
    __syncthreads();

    const int i  = t >> 2;
    const int j0 = (t & 3) * 16;

    float a[16] = {};
    for (int d = 0; d < 64; ++d) {
        float qv = Qs[i][d];
        #pragma unroll
        for (int jj = 0; jj < 16; ++jj) a[jj] += qv * Kt[d][j0 + jj];
    }
    #pragma unroll
    for (int jj = 0; jj < 16; ++jj)
        As[i][j0 + jj] = (j0 + jj <= i) ? a[jj] : 0.f;
    __syncthreads();

    float o[16] = {};
    for (int d = 0; d < 64; ++d) {
        float qv = Qs[i][d];
        #pragma unroll
        for (int jj = 0; jj < 16; ++jj) o[jj] += qv * Ps[d * 64 + j0 + jj];
    }
    for (int j = 0; j < 64; ++j) {
        float av = As[i][j];
        #pragma unroll
        for (int jj = 0; jj < 16; ++jj) o[jj] += av * Vs[j * 64 + j0 + jj];
    }

    const int b = bh >> 3;
    const int h = bh & 7;
    const int n = c * 64 + i;
    const int rg = b * NN + n;
    bf16* dst = aug + (size_t)rg * KAUG + h * HDIM + j0;
    #pragma unroll
    for (int jj = 0; jj < 16; ++jj) {
        float v = o[jj];
        bf16 hi = (bf16)v;
        bf16 lo = (bf16)(v - (float)hi);
        dst[jj]        = hi;
        dst[512 + jj]  = hi;
        dst[1024 + jj] = lo;
    }
}

// ---------------------------------------------------------------------------
extern "C" void kernel_launch(void* const* d_in, const int* in_sizes, int n_in,
                              void* d_out, int out_size, void* d_ws, size_t ws_size,
                              hipStream_t stream)
{
    (void)in_sizes; (void)n_in; (void)out_size; (void)ws_size;

    const float* x  = (const float*)d_in[0];
    const float* Wq = (const float*)d_in[1];
    const float* Wk = (const float*)d_in[2];
    const float* Wv = (const float*)d_in[3];
    const float* Wo = (const float*)d_in[4];
    const float* bq = (const float*)d_in[5];
    const float* bk = (const float*)d_in[6];
    const float* bv = (const float*)d_in[7];
    const float* bo = (const float*)d_in[8];
    float* out = (float*)d_out;

    // workspace layout (bytes): qb 8M | kb 8M | vb 8M | st 8M | xa 12M | wa 6M = 50MB
    char* ws = (char*)d_ws;
    float* qb = (float*)(ws);
    float* kb = (float*)(ws + (size_t)8  * 1024 * 1024);
    float* vb = (float*)(ws + (size_t)16 * 1024 * 1024);
    float* st = (float*)(ws + (size_t)24 * 1024 * 1024);
    bf16*  xa = (bf16*) (ws + (size_t)32 * 1024 * 1024);   // aliased by attn_aug later
    bf16*  wa = (bf16*) (ws + (size_t)44 * 1024 * 1024);

    dim3 blk(256);

    split_x<<<dim3(2048), blk, 0, stream>>>(x, xa);
    split_w<<<dim3(256, 4), blk, 0, stream>>>(Wq, Wk, Wv, Wo, wa);

    // fused q,k,v projections (z = 0,1,2)
    mm_aug<0><<<dim3(32, 4, 3), blk, 0, stream>>>(xa, wa, bq, bk, bv, qb);

    chunk_state<<<dim3(32, NCHUNK), blk, 0, stream>>>(kb, vb, st);
    prefix_scan<<<dim3(32), blk, 0, stream>>>(st);
    attn_chunk<<<dim3(32, NCHUNK), blk, 0, stream>>>(qb, kb, vb, st, xa);

    // out projection from augmented attn (xa)
    mm_aug<1><<<dim3(32, 4), blk, 0, stream>>>(xa, wa + (size_t)3 * WMAT, bo, nullptr, nullptr, out);
}

// Round 3
// 119.568 us; speedup vs baseline: 2.1309x; 1.2536x over previous
//
#include <hip/hip_runtime.h>
#include <cmath>

// Problem constants
#define BB 4
#define NN 1024
#define DD 512
#define HH 8
#define HDIM 64
#define ROWS (BB * NN)      // 4096
#define NCHUNK 16
#define KAUG 1536           // split-bf16 augmented K: [hi | hi | lo] x [hi | lo | hi]
#define WMAT (512 * KAUG)   // one augmented weight matrix, elems
#define PLANE ((size_t)ROWS * DD)

typedef __bf16 bf16;
typedef bf16  bf16x8 __attribute__((ext_vector_type(8)));
typedef bf16  bf16x4 __attribute__((ext_vector_type(4)));
typedef float f32x4  __attribute__((ext_vector_type(4)));

#define GLOAD_LDS16(g, l) \
    __builtin_amdgcn_global_load_lds((const __attribute__((address_space(1))) void*)(g), \
                                     (__attribute__((address_space(3))) void*)(l), 16, 0, 0)

// ---------------------------------------------------------------------------
// Split fp32 -> augmented bf16 rows: [hi(512) | hi(512) | lo(512)]
// ---------------------------------------------------------------------------
__global__ __launch_bounds__(256)
void split_x(const float* __restrict__ x, bf16* __restrict__ xa)
{
    int t = blockIdx.x * 256 + threadIdx.x;
    float4 v = ((const float4*)x)[t];
    float a[4] = {v.x, v.y, v.z, v.w};
    int r = t >> 7;
    int c = (t & 127) * 4;
    bf16x4 hi, lo;
    #pragma unroll
    for (int i = 0; i < 4; ++i) {
        bf16 h = (bf16)a[i];
        hi[i] = h;
        lo[i] = (bf16)(a[i] - (float)h);
    }
    bf16* dst = xa + (size_t)r * KAUG + c;
    *(bf16x4*)(dst)        = hi;
    *(bf16x4*)(dst + 512)  = hi;
    *(bf16x4*)(dst + 1024) = lo;
}

// Weights: [hi(512) | lo(512) | hi(512)]  (pairs with A's [hi|hi|lo])
__global__ __launch_bounds__(256)
void split_w(const float* __restrict__ Wq, const float* __restrict__ Wk,
             const float* __restrict__ Wv, const float* __restrict__ Wo,
             bf16* __restrict__ wa)
{
    int m = blockIdx.y;
    const float* W = (m == 0) ? Wq : (m == 1) ? Wk : (m == 2) ? Wv : Wo;
    int t = blockIdx.x * 256 + threadIdx.x;
    float4 v = ((const float4*)W)[t];
    float a[4] = {v.x, v.y, v.z, v.w};
    int r = t >> 7;
    int c = (t & 127) * 4;
    bf16x4 hi, lo;
    #pragma unroll
    for (int i = 0; i < 4; ++i) {
        bf16 h = (bf16)a[i];
        hi[i] = h;
        lo[i] = (bf16)(a[i] - (float)h);
    }
    bf16* dst = wa + (size_t)m * WMAT + (size_t)r * KAUG + c;
    *(bf16x4*)(dst)        = hi;
    *(bf16x4*)(dst + 512)  = lo;
    *(bf16x4*)(dst + 1024) = hi;
}

// ---------------------------------------------------------------------------
// MFMA GEMM: 64x128 tile, BK=64, 4 waves (2x2, each 32x64), 16x16x32 bf16.
// OUTMODE 0: grid (64,4,3): z = matrix (q,k,v); full K; elu+L2norm for z<2;
//            write (B,H,N,64) f32 planes.
// OUTMODE 1: grid (64,4,3): z = K-segment (split-K); atomicAdd into out,
//            bias added by z==0.
// ---------------------------------------------------------------------------
template<int OUTMODE>
__global__ __launch_bounds__(256)
void mm_aug(const bf16* __restrict__ A, const bf16* __restrict__ Wbase,
            const float* __restrict__ b0, const float* __restrict__ b1,
            const float* __restrict__ b2, float* __restrict__ obase)
{
    __shared__ bf16 As[64 * 64];    // 8KB  [row][k]
    __shared__ bf16 Bs[128 * 64];   // 16KB [col][k]

    const int t    = threadIdx.x;
    const int lane = t & 63;
    const int wid  = t >> 6;
    const int wr   = wid >> 1;
    const int wc   = wid & 1;
    const int l16  = lane & 15;
    const int g16  = lane >> 4;

    const int r0 = blockIdx.x * 64;
    const int c0 = blockIdx.y * 128;
    const int z  = blockIdx.z;

    const bf16* Wm = (OUTMODE == 0) ? Wbase + (size_t)z * WMAT : Wbase;

    const int kt_begin = (OUTMODE == 0) ? 0  : z * 8;
    const int kt_end   = (OUTMODE == 0) ? 24 : z * 8 + 8;

    f32x4 acc[2][4] = {};

    for (int kt = kt_begin; kt < kt_end; ++kt) {
        const int k0 = kt * 64;
        // stage A (8KB): 2 chunks/thread; B (16KB): 4 chunks/thread
        #pragma unroll
        for (int i = 0; i < 2; ++i) {
            int f = i * 256 + wid * 64 + lane;
            GLOAD_LDS16(A + (size_t)(r0 + (f >> 3)) * KAUG + k0 + ((f & 7) << 3),
                        As + i * 2048 + wid * 512);
        }
        #pragma unroll
        for (int i = 0; i < 4; ++i) {
            int f = i * 256 + wid * 64 + lane;
            GLOAD_LDS16(Wm + (size_t)(c0 + (f >> 3)) * KAUG + k0 + ((f & 7) << 3),
                        Bs + i * 2048 + wid * 512);
        }
        __syncthreads();

        bf16x8 af[2][2], bfr[4][2];
        #pragma unroll
        for (int mi = 0; mi < 2; ++mi)
            #pragma unroll
            for (int kk = 0; kk < 2; ++kk)
                af[mi][kk] = *(const bf16x8*)(As + (wr * 32 + mi * 16 + l16) * 64 + kk * 32 + g16 * 8);
        #pragma unroll
        for (int ni = 0; ni < 4; ++ni)
            #pragma unroll
            for (int kk = 0; kk < 2; ++kk)
                bfr[ni][kk] = *(const bf16x8*)(Bs + (wc * 64 + ni * 16 + l16) * 64 + kk * 32 + g16 * 8);
        #pragma unroll
        for (int kk = 0; kk < 2; ++kk)
            #pragma unroll
            for (int mi = 0; mi < 2; ++mi)
                #pragma unroll
                for (int ni = 0; ni < 4; ++ni)
                    acc[mi][ni] = __builtin_amdgcn_mfma_f32_16x16x32_bf16(af[mi][kk], bfr[ni][kk], acc[mi][ni], 0, 0, 0);
        __syncthreads();
    }

    if (OUTMODE == 1) {
        #pragma unroll
        for (int mi = 0; mi < 2; ++mi)
            #pragma unroll
            for (int ni = 0; ni < 4; ++ni) {
                int cg = c0 + wc * 64 + ni * 16 + l16;
                float bv = (z == 0) ? b0[cg] : 0.f;
                #pragma unroll
                for (int r = 0; r < 4; ++r) {
                    int rg = r0 + wr * 32 + mi * 16 + g16 * 4 + r;
                    atomicAdd(&obase[(size_t)rg * DD + cg], acc[mi][ni][r] + bv);
                }
            }
    } else {
        const float* bias = (z == 0) ? b0 : (z == 1) ? b1 : b2;
        float* outp = obase + (size_t)z * PLANE;

        #pragma unroll
        for (int mi = 0; mi < 2; ++mi)
            #pragma unroll
            for (int ni = 0; ni < 4; ++ni) {
                float bv = bias[c0 + wc * 64 + ni * 16 + l16];
                #pragma unroll
                for (int r = 0; r < 4; ++r) {
                    float v = acc[mi][ni][r] + bv;
                    if (z < 2) v = (v > 0.f) ? v : expm1f(v);
                    acc[mi][ni][r] = v;
                }
            }
        if (z < 2) {
            #pragma unroll
            for (int mi = 0; mi < 2; ++mi)
                #pragma unroll
                for (int r = 0; r < 4; ++r) {
                    float ss = 0.f;
                    #pragma unroll
                    for (int ni = 0; ni < 4; ++ni) ss += acc[mi][ni][r] * acc[mi][ni][r];
                    ss += __shfl_xor(ss, 1);
                    ss += __shfl_xor(ss, 2);
                    ss += __shfl_xor(ss, 4);
                    ss += __shfl_xor(ss, 8);
                    float sc = 1.f / fmaxf(sqrtf(ss), 1e-12f);
                    #pragma unroll
                    for (int ni = 0; ni < 4; ++ni) acc[mi][ni][r] *= sc;
                }
        }
        const int h = (c0 >> 6) + wc;
        #pragma unroll
        for (int mi = 0; mi < 2; ++mi)
            #pragma unroll
            for (int r = 0; r < 4; ++r) {
                int rg = r0 + wr * 32 + mi * 16 + g16 * 4 + r;
                int b = rg >> 10, n = rg & 1023;
                float* dst = outp + ((size_t)(b * HH + h) * NN + n) * HDIM;
                #pragma unroll
                for (int ni = 0; ni < 4; ++ni) dst[ni * 16 + l16] = acc[mi][ni][r];
            }
    }
}

// ---------------------------------------------------------------------------
// Per-chunk state: S_c[d][e] = sum_{n in chunk} K[n][d] * V[n][e]   (64x64)
// ---------------------------------------------------------------------------
__global__ __launch_bounds__(256)
void chunk_state(const float* __restrict__ kb, const float* __restrict__ vb,
                 float* __restrict__ S)
{
    __shared__ float Ks[64 * 64];
    __shared__ float Vs[64 * 64];

    const int bh = blockIdx.x;
    const int ch = blockIdx.y;
    const int t  = threadIdx.x;

    const float4* kg4 = (const float4*)(kb + ((size_t)bh * NN + ch * 64) * HDIM);
    const float4* vg4 = (const float4*)(vb + ((size_t)bh * NN + ch * 64) * HDIM);

    #pragma unroll
    for (int i = 0; i < 4; ++i) {
        int f4 = t + i * 256;
        ((float4*)Ks)[f4] = kg4[f4];
        ((float4*)Vs)[f4] = vg4[f4];
    }
    __syncthreads();

    const int d  = t >> 2;
    const int e0 = (t & 3) * 16;
    f32x4 acc[4] = {};
    for (int n = 0; n < 64; ++n) {
        float kv = Ks[n * 64 + d];
        const f32x4* vp = (const f32x4*)(Vs + n * 64 + e0);
        #pragma unroll
        for (int c = 0; c < 4; ++c) acc[c] += kv * vp[c];
    }
    float* sg = S + ((size_t)bh * NCHUNK + ch) * 4096;
    f32x4* sp = (f32x4*)(sg + d * 64 + e0);
    #pragma unroll
    for (int c = 0; c < 4; ++c) sp[c] = acc[c];
}

// ---------------------------------------------------------------------------
// Exclusive prefix over the 16 chunk states per (b,h) — 512 blocks
// ---------------------------------------------------------------------------
__global__ __launch_bounds__(256)
void prefix_scan(float* __restrict__ S)
{
    const int bh  = blockIdx.x;
    const int idx = blockIdx.y * 256 + threadIdx.x;
    float* sg = S + (size_t)bh * NCHUNK * 4096;
    float run = 0.f;
    #pragma unroll
    for (int c = 0; c < NCHUNK; ++c) {
        float v = sg[c * 4096 + idx];
        sg[c * 4096 + idx] = run;
        run += v;
    }
}

// ---------------------------------------------------------------------------
// Chunk attention: O = Q @ P + tril(Q K^T) @ V -> split-bf16 augmented rows.
// Order: QP (reads P) -> QK^T -> scores overlay P's buffer -> AV.
// ---------------------------------------------------------------------------
__global__ __launch_bounds__(256)
void attn_chunk(const float* __restrict__ qb, const float* __restrict__ kb,
                const float* __restrict__ vb, const float* __restrict__ S,
                bf16* __restrict__ aug)
{
    __shared__ float Qs[64][68];   // [i][d], rows 16B-aligned (68*4=272)
    __shared__ float Kt[64][68];   // [d][j]
    __shared__ float PA[64 * 68];  // P (first 4096 floats) then scores [i*68+j]
    __shared__ float Vs[64 * 64];

    const int bh = blockIdx.x;
    const int ch = blockIdx.y;
    const int t  = threadIdx.x;

    const float4* qg4 = (const float4*)(qb + ((size_t)bh * NN + ch * 64) * HDIM);
    const float4* kg4 = (const float4*)(kb + ((size_t)bh * NN + ch * 64) * HDIM);
    const float4* vg4 = (const float4*)(vb + ((size_t)bh * NN + ch * 64) * HDIM);
    const float4* sg4 = (const float4*)(S + ((size_t)bh * NCHUNK + ch) * 4096);

    #pragma unroll
    for (int i = 0; i < 4; ++i) {
        int f4 = t + i * 256;
        int n  = f4 >> 4;
        int d4 = (f4 & 15) * 4;
        float4 q4 = qg4[f4];
        Qs[n][d4 + 0] = q4.x; Qs[n][d4 + 1] = q4.y; Qs[n][d4 + 2] = q4.z; Qs[n][d4 + 3] = q4.w;
        float4 k4 = kg4[f4];
        Kt[d4 + 0][n] = k4.x; Kt[d4 + 1][n] = k4.y; Kt[d4 + 2][n] = k4.z; Kt[d4 + 3][n] = k4.w;
        ((float4*)Vs)[f4] = vg4[f4];
        ((float4*)PA)[f4] = sg4[f4];
    }
    __syncthreads();

    const int i  = t >> 2;
    const int j0 = (t & 3) * 16;

    // o = Q @ P
    f32x4 o4[4] = {};
    for (int dd = 0; dd < 16; ++dd) {
        f32x4 qv = *(const f32x4*)&Qs[i][dd * 4];
        #pragma unroll
        for (int l = 0; l < 4; ++l) {
            const f32x4* p = (const f32x4*)(PA + (dd * 4 + l) * 64 + j0);
            #pragma unroll
            for (int c = 0; c < 4; ++c) o4[c] += qv[l] * p[c];
        }
    }
    __syncthreads();   // all P reads done before overlay

    // scores a = Q K^T (masked), write into PA as [i][j] stride 68
    f32x4 a4[4] = {};
    for (int dd = 0; dd < 16; ++dd) {
        f32x4 qv = *(const f32x4*)&Qs[i][dd * 4];
        #pragma unroll
        for (int l = 0; l < 4; ++l) {
            const f32x4* kp = (const f32x4*)&Kt[dd * 4 + l][j0];
            #pragma unroll
            for (int c = 0; c < 4; ++c) a4[c] += qv[l] * kp[c];
        }
    }
    #pragma unroll
    for (int c = 0; c < 4; ++c)
        #pragma unroll
        for (int l = 0; l < 4; ++l) {
            int j = j0 + c * 4 + l;
            PA[i * 68 + j] = (j <= i) ? a4[c][l] : 0.f;
        }
    __syncthreads();

    // o += A @ V
    for (int j = 0; j < 64; ++j) {
        float av = PA[i * 68 + j];
        const f32x4* vp = (const f32x4*)(Vs + j * 64 + j0);
        #pragma unroll
        for (int c = 0; c < 4; ++c) o4[c] += av * vp[c];
    }

    // emit split-bf16 augmented row segment
    const int b = bh >> 3;
    const int h = bh & 7;
    const int rg = b * NN + ch * 64 + i;
    bf16* dst = aug + (size_t)rg * KAUG + h * HDIM + j0;
    bf16x8 hi[2], lo[2];
    #pragma unroll
    for (int c = 0; c < 4; ++c)
        #pragma unroll
        for (int l = 0; l < 4; ++l) {
            int idx = c * 4 + l;
            float v = o4[c][l];
            bf16 hv = (bf16)v;
            hi[idx >> 3][idx & 7] = hv;
            lo[idx >> 3][idx & 7] = (bf16)(v - (float)hv);
        }
    *(bf16x8*)(dst)          = hi[0];
    *(bf16x8*)(dst + 8)      = hi[1];
    *(bf16x8*)(dst + 512)    = hi[0];
    *(bf16x8*)(dst + 520)    = hi[1];
    *(bf16x8*)(dst + 1024)   = lo[0];
    *(bf16x8*)(dst + 1032)   = lo[1];
}

// ---------------------------------------------------------------------------
extern "C" void kernel_launch(void* const* d_in, const int* in_sizes, int n_in,
                              void* d_out, int out_size, void* d_ws, size_t ws_size,
                              hipStream_t stream)
{
    (void)in_sizes; (void)n_in; (void)ws_size;

    const float* x  = (const float*)d_in[0];
    const float* Wq = (const float*)d_in[1];
    const float* Wk = (const float*)d_in[2];
    const float* Wv = (const float*)d_in[3];
    const float* Wo = (const float*)d_in[4];
    const float* bq = (const float*)d_in[5];
    const float* bk = (const float*)d_in[6];
    const float* bv = (const float*)d_in[7];
    const float* bo = (const float*)d_in[8];
    float* out = (float*)d_out;

    // workspace: qb 8M | kb 8M | vb 8M | st 8M | xa 12M | wa 12M
    char* ws = (char*)d_ws;
    float* qb = (float*)(ws);
    float* kb = (float*)(ws + (size_t)8  * 1024 * 1024);
    float* vb = (float*)(ws + (size_t)16 * 1024 * 1024);
    float* st = (float*)(ws + (size_t)24 * 1024 * 1024);
    bf16*  xa = (bf16*) (ws + (size_t)32 * 1024 * 1024);   // reused as attn aug
    bf16*  wa = (bf16*) (ws + (size_t)44 * 1024 * 1024);

    dim3 blk(256);

    hipMemsetAsync(out, 0, (size_t)out_size * sizeof(float), stream);

    split_x<<<dim3(2048), blk, 0, stream>>>(x, xa);
    split_w<<<dim3(256, 4), blk, 0, stream>>>(Wq, Wk, Wv, Wo, wa);

    // fused q,k,v projections
    mm_aug<0><<<dim3(64, 4, 3), blk, 0, stream>>>(xa, wa, bq, bk, bv, qb);

    chunk_state<<<dim3(32, NCHUNK), blk, 0, stream>>>(kb, vb, st);
    prefix_scan<<<dim3(32, 16), blk, 0, stream>>>(st);
    attn_chunk<<<dim3(32, NCHUNK), blk, 0, stream>>>(qb, kb, vb, st, xa);

    // out projection, split-K over the 3 augmented segments
    mm_aug<1><<<dim3(64, 4, 3), blk, 0, stream>>>(xa, wa + (size_t)3 * WMAT, bo, nullptr, nullptr, out);
}

// Round 4
// 97.131 us; speedup vs baseline: 2.6232x; 1.2310x over previous
//
#include <hip/hip_runtime.h>
#include <cmath>

// Problem constants
#define BB 4
#define NN 1024
#define DD 512
#define HH 8
#define HDIM 64
#define ROWS (BB * NN)      // 4096
#define NCHUNK 16
#define KAUG 1536           // split-bf16 augmented K: [hi | hi | lo] x [hi | lo | hi]
#define WMAT (512 * KAUG)   // one augmented weight matrix, elems
#define PLANE ((size_t)ROWS * DD)

typedef __bf16 bf16;
typedef bf16  bf16x8 __attribute__((ext_vector_type(8)));
typedef bf16  bf16x4 __attribute__((ext_vector_type(4)));
typedef float f32x4  __attribute__((ext_vector_type(4)));

#define GLOAD_LDS16(g, l) \
    __builtin_amdgcn_global_load_lds((const __attribute__((address_space(1))) void*)(g), \
                                     (__attribute__((address_space(3))) void*)(l), 16, 0, 0)

// ---------------------------------------------------------------------------
// Split fp32 -> augmented bf16 rows: [hi(512) | hi(512) | lo(512)]
// ---------------------------------------------------------------------------
__global__ __launch_bounds__(256)
void split_x(const float* __restrict__ x, bf16* __restrict__ xa)
{
    int t = blockIdx.x * 256 + threadIdx.x;
    float4 v = ((const float4*)x)[t];
    float a[4] = {v.x, v.y, v.z, v.w};
    int r = t >> 7;
    int c = (t & 127) * 4;
    bf16x4 hi, lo;
    #pragma unroll
    for (int i = 0; i < 4; ++i) {
        bf16 h = (bf16)a[i];
        hi[i] = h;
        lo[i] = (bf16)(a[i] - (float)h);
    }
    bf16* dst = xa + (size_t)r * KAUG + c;
    *(bf16x4*)(dst)        = hi;
    *(bf16x4*)(dst + 512)  = hi;
    *(bf16x4*)(dst + 1024) = lo;
}

// Weights: [hi(512) | lo(512) | hi(512)]  (pairs with A's [hi|hi|lo])
__global__ __launch_bounds__(256)
void split_w(const float* __restrict__ Wq, const float* __restrict__ Wk,
             const float* __restrict__ Wv, const float* __restrict__ Wo,
             bf16* __restrict__ wa)
{
    int m = blockIdx.y;
    const float* W = (m == 0) ? Wq : (m == 1) ? Wk : (m == 2) ? Wv : Wo;
    int t = blockIdx.x * 256 + threadIdx.x;
    float4 v = ((const float4*)W)[t];
    float a[4] = {v.x, v.y, v.z, v.w};
    int r = t >> 7;
    int c = (t & 127) * 4;
    bf16x4 hi, lo;
    #pragma unroll
    for (int i = 0; i < 4; ++i) {
        bf16 h = (bf16)a[i];
        hi[i] = h;
        lo[i] = (bf16)(a[i] - (float)h);
    }
    bf16* dst = wa + (size_t)m * WMAT + (size_t)r * KAUG + c;
    *(bf16x4*)(dst)        = hi;
    *(bf16x4*)(dst + 512)  = lo;
    *(bf16x4*)(dst + 1024) = hi;
}

// ---------------------------------------------------------------------------
// MFMA GEMM, double-buffered LDS + prefetch, read-side XOR swizzle.
// Tile rows are 64 bf16 (128 B): slot s of row r holds source col (s ^ (r&7)).
// OUTMODE 0: BM=64,BN=128, grid (64,4,3): z = matrix (q,k,v); elu+L2norm z<2;
//            write (B,H,N,64) f32 planes.
// OUTMODE 1: BM=64,BN=64, grid (64,8): full K, plain store + bias -> out.
// ---------------------------------------------------------------------------
template<int OUTMODE>
__global__ __launch_bounds__(256)
void mm_aug(const bf16* __restrict__ A, const bf16* __restrict__ Wbase,
            const float* __restrict__ b0, const float* __restrict__ b1,
            const float* __restrict__ b2, float* __restrict__ obase)
{
    constexpr int BN = (OUTMODE == 0) ? 128 : 64;
    constexpr int NW = BN / 32;               // N-frags per wave (4 or 2)

    __shared__ __align__(16) bf16 As[2][64 * 64];
    __shared__ __align__(16) bf16 Bs[2][BN * 64];

    const int t    = threadIdx.x;
    const int lane = t & 63;
    const int wid  = t >> 6;
    const int wr   = wid >> 1;
    const int wc   = wid & 1;
    const int l16  = lane & 15;
    const int g16  = lane >> 4;

    const int r0 = blockIdx.x * 64;
    const int c0 = blockIdx.y * BN;
    const int z  = (OUTMODE == 0) ? blockIdx.z : 0;

    const bf16* Wm = (OUTMODE == 0) ? Wbase + (size_t)z * WMAT : Wbase;

    auto stage = [&](int buf, int kt) {
        const int k0 = kt * 64;
        #pragma unroll
        for (int i = 0; i < 2; ++i) {
            int f = i * 256 + wid * 64 + lane;
            int r = f >> 3, s = f & 7;
            int sc = s ^ (r & 7);
            GLOAD_LDS16(A + (size_t)(r0 + r) * KAUG + k0 + sc * 8,
                        &As[buf][(i * 256 + wid * 64) * 8]);
        }
        #pragma unroll
        for (int i = 0; i < BN / 32; ++i) {
            int f = i * 256 + wid * 64 + lane;
            int r = f >> 3, s = f & 7;
            int sc = s ^ (r & 7);
            GLOAD_LDS16(Wm + (size_t)(c0 + r) * KAUG + k0 + sc * 8,
                        &Bs[buf][(i * 256 + wid * 64) * 8]);
        }
    };

    f32x4 acc[2][NW] = {};

    int cur = 0;
    stage(0, 0);
    __syncthreads();

    for (int kt = 0; kt < 24; ++kt) {
        if (kt + 1 < 24) stage(cur ^ 1, kt + 1);

        bf16x8 af[2][2], bfr[NW][2];
        #pragma unroll
        for (int mi = 0; mi < 2; ++mi)
            #pragma unroll
            for (int kk = 0; kk < 2; ++kk) {
                int lr = wr * 32 + mi * 16 + l16;
                int c  = kk * 4 + g16;
                af[mi][kk] = *(const bf16x8*)(&As[cur][lr * 64 + ((c ^ (lr & 7)) * 8)]);
            }
        #pragma unroll
        for (int ni = 0; ni < NW; ++ni)
            #pragma unroll
            for (int kk = 0; kk < 2; ++kk) {
                int lr = wc * (BN / 2) + ni * 16 + l16;
                int c  = kk * 4 + g16;
                bfr[ni][kk] = *(const bf16x8*)(&Bs[cur][lr * 64 + ((c ^ (lr & 7)) * 8)]);
            }
        #pragma unroll
        for (int kk = 0; kk < 2; ++kk)
            #pragma unroll
            for (int mi = 0; mi < 2; ++mi)
                #pragma unroll
                for (int ni = 0; ni < NW; ++ni)
                    acc[mi][ni] = __builtin_amdgcn_mfma_f32_16x16x32_bf16(af[mi][kk], bfr[ni][kk], acc[mi][ni], 0, 0, 0);
        __syncthreads();
        cur ^= 1;
    }

    if (OUTMODE == 1) {
        #pragma unroll
        for (int mi = 0; mi < 2; ++mi)
            #pragma unroll
            for (int ni = 0; ni < NW; ++ni) {
                int cg = c0 + wc * (BN / 2) + ni * 16 + l16;
                float bv = b0[cg];
                #pragma unroll
                for (int r = 0; r < 4; ++r) {
                    int rg = r0 + wr * 32 + mi * 16 + g16 * 4 + r;
                    obase[(size_t)rg * DD + cg] = acc[mi][ni][r] + bv;
                }
            }
    } else {
        const float* bias = (z == 0) ? b0 : (z == 1) ? b1 : b2;
        float* outp = obase + (size_t)z * PLANE;

        #pragma unroll
        for (int mi = 0; mi < 2; ++mi)
            #pragma unroll
            for (int ni = 0; ni < NW; ++ni) {
                float bv = bias[c0 + wc * 64 + ni * 16 + l16];
                #pragma unroll
                for (int r = 0; r < 4; ++r) {
                    float v = acc[mi][ni][r] + bv;
                    if (z < 2) v = (v > 0.f) ? v : expm1f(v);
                    acc[mi][ni][r] = v;
                }
            }
        if (z < 2) {
            #pragma unroll
            for (int mi = 0; mi < 2; ++mi)
                #pragma unroll
                for (int r = 0; r < 4; ++r) {
                    float ss = 0.f;
                    #pragma unroll
                    for (int ni = 0; ni < NW; ++ni) ss += acc[mi][ni][r] * acc[mi][ni][r];
                    ss += __shfl_xor(ss, 1);
                    ss += __shfl_xor(ss, 2);
                    ss += __shfl_xor(ss, 4);
                    ss += __shfl_xor(ss, 8);
                    float sc = 1.f / fmaxf(sqrtf(ss), 1e-12f);
                    #pragma unroll
                    for (int ni = 0; ni < NW; ++ni) acc[mi][ni][r] *= sc;
                }
        }
        const int h = (c0 >> 6) + wc;
        #pragma unroll
        for (int mi = 0; mi < 2; ++mi)
            #pragma unroll
            for (int r = 0; r < 4; ++r) {
                int rg = r0 + wr * 32 + mi * 16 + g16 * 4 + r;
                int b = rg >> 10, n = rg & 1023;
                float* dst = outp + ((size_t)(b * HH + h) * NN + n) * HDIM;
                #pragma unroll
                for (int ni = 0; ni < NW; ++ni) dst[ni * 16 + l16] = acc[mi][ni][r];
            }
    }
}

// ---------------------------------------------------------------------------
// Per-chunk state: S_c[d][e] = sum_{n in chunk} K[n][d] * V[n][e]   (64x64)
// 4x4 register tile per thread.
// ---------------------------------------------------------------------------
__global__ __launch_bounds__(256)
void chunk_state(const float* __restrict__ kb, const float* __restrict__ vb,
                 float* __restrict__ S)
{
    __shared__ float Ks[64 * 64];
    __shared__ float Vs[64 * 64];

    const int bh = blockIdx.x;
    const int ch = blockIdx.y;
    const int t  = threadIdx.x;

    const float4* kg4 = (const float4*)(kb + ((size_t)bh * NN + ch * 64) * HDIM);
    const float4* vg4 = (const float4*)(vb + ((size_t)bh * NN + ch * 64) * HDIM);

    #pragma unroll
    for (int i = 0; i < 4; ++i) {
        int f4 = t + i * 256;
        ((float4*)Ks)[f4] = kg4[f4];
        ((float4*)Vs)[f4] = vg4[f4];
    }
    __syncthreads();

    const int d0 = (t >> 4) * 4;
    const int e0 = (t & 15) * 4;
    f32x4 acc[4] = {};
    for (int n = 0; n < 64; ++n) {
        f32x4 kv = *(const f32x4*)(Ks + n * 64 + d0);
        f32x4 vv = *(const f32x4*)(Vs + n * 64 + e0);
        #pragma unroll
        for (int di = 0; di < 4; ++di) acc[di] += kv[di] * vv;
    }
    float* sg = S + ((size_t)bh * NCHUNK + ch) * 4096;
    #pragma unroll
    for (int di = 0; di < 4; ++di)
        *(f32x4*)(sg + (d0 + di) * 64 + e0) = acc[di];
}

// ---------------------------------------------------------------------------
// Exclusive prefix over the 16 chunk states per (b,h) — 512 blocks
// ---------------------------------------------------------------------------
__global__ __launch_bounds__(256)
void prefix_scan(float* __restrict__ S)
{
    const int bh  = blockIdx.x;
    const int idx = blockIdx.y * 256 + threadIdx.x;
    float* sg = S + (size_t)bh * NCHUNK * 4096;
    float run = 0.f;
    #pragma unroll
    for (int c = 0; c < NCHUNK; ++c) {
        float v = sg[c * 4096 + idx];
        sg[c * 4096 + idx] = run;
        run += v;
    }
}

// ---------------------------------------------------------------------------
// Chunk attention: O = Q @ P + tril(Q K^T) @ V -> split-bf16 augmented rows.
// 4x4 register tiles; scores overlay P's LDS after QP completes.
// ---------------------------------------------------------------------------
__global__ __launch_bounds__(256)
void attn_chunk(const float* __restrict__ qb, const float* __restrict__ kb,
                const float* __restrict__ vb, const float* __restrict__ S,
                bf16* __restrict__ aug)
{
    __shared__ float Qs[64][68];   // [i][d], rows 16B-aligned
    __shared__ float Kt[64][68];   // [d][j]
    __shared__ float PA[64 * 68];  // P [d*64+e] first, then scores [i*68+j]
    __shared__ float Vs[64 * 64];

    const int bh = blockIdx.x;
    const int ch = blockIdx.y;
    const int t  = threadIdx.x;

    const float4* qg4 = (const float4*)(qb + ((size_t)bh * NN + ch * 64) * HDIM);
    const float4* kg4 = (const float4*)(kb + ((size_t)bh * NN + ch * 64) * HDIM);
    const float4* vg4 = (const float4*)(vb + ((size_t)bh * NN + ch * 64) * HDIM);
    const float4* sg4 = (const float4*)(S + ((size_t)bh * NCHUNK + ch) * 4096);

    #pragma unroll
    for (int i = 0; i < 4; ++i) {
        int f4 = t + i * 256;
        int n  = f4 >> 4;
        int d4 = (f4 & 15) * 4;
        float4 q4 = qg4[f4];
        Qs[n][d4 + 0] = q4.x; Qs[n][d4 + 1] = q4.y; Qs[n][d4 + 2] = q4.z; Qs[n][d4 + 3] = q4.w;
        float4 k4 = kg4[f4];
        Kt[d4 + 0][n] = k4.x; Kt[d4 + 1][n] = k4.y; Kt[d4 + 2][n] = k4.z; Kt[d4 + 3][n] = k4.w;
        ((float4*)Vs)[f4] = vg4[f4];
        ((float4*)PA)[f4] = sg4[f4];
    }
    __syncthreads();

    const int r  = (t >> 4) * 4;   // 4 output rows
    const int cN = (t & 15) * 4;   // 4 output cols

    // o = Q @ P
    f32x4 o[4] = {};
    for (int d4 = 0; d4 < 16; ++d4) {
        f32x4 q[4], p[4];
        #pragma unroll
        for (int ri = 0; ri < 4; ++ri) q[ri] = *(const f32x4*)&Qs[r + ri][d4 * 4];
        #pragma unroll
        for (int l = 0; l < 4; ++l) p[l] = *(const f32x4*)(PA + (d4 * 4 + l) * 64 + cN);
        #pragma unroll
        for (int ri = 0; ri < 4; ++ri)
            #pragma unroll
            for (int l = 0; l < 4; ++l) o[ri] += q[ri][l] * p[l];
    }

    // scores a = Q K^T (pre-barrier: touches only Qs/Kt)
    f32x4 a[4] = {};
    for (int d4 = 0; d4 < 16; ++d4) {
        f32x4 q[4], kv[4];
        #pragma unroll
        for (int ri = 0; ri < 4; ++ri) q[ri] = *(const f32x4*)&Qs[r + ri][d4 * 4];
        #pragma unroll
        for (int l = 0; l < 4; ++l) kv[l] = *(const f32x4*)&Kt[d4 * 4 + l][cN];
        #pragma unroll
        for (int ri = 0; ri < 4; ++ri)
            #pragma unroll
            for (int l = 0; l < 4; ++l) a[ri] += q[ri][l] * kv[l];
    }
    __syncthreads();   // all P reads done -> safe to overlay

    #pragma unroll
    for (int ri = 0; ri < 4; ++ri)
        #pragma unroll
        for (int l = 0; l < 4; ++l) {
            int j = cN + l;
            PA[(r + ri) * 68 + j] = (j <= r + ri) ? a[ri][l] : 0.f;
        }
    __syncthreads();

    // o += A @ V
    for (int j4 = 0; j4 < 16; ++j4) {
        f32x4 av[4], v[4];
        #pragma unroll
        for (int ri = 0; ri < 4; ++ri) av[ri] = *(const f32x4*)(PA + (r + ri) * 68 + j4 * 4);
        #pragma unroll
        for (int l = 0; l < 4; ++l) v[l] = *(const f32x4*)(Vs + (j4 * 4 + l) * 64 + cN);
        #pragma unroll
        for (int ri = 0; ri < 4; ++ri)
            #pragma unroll
            for (int l = 0; l < 4; ++l) o[ri] += av[ri][l] * v[l];
    }

    // emit split-bf16 augmented row segments
    const int b = bh >> 3;
    const int h = bh & 7;
    #pragma unroll
    for (int ri = 0; ri < 4; ++ri) {
        const int rg = b * NN + ch * 64 + r + ri;
        bf16* dst = aug + (size_t)rg * KAUG + h * HDIM + cN;
        bf16x4 hi, lo;
        #pragma unroll
        for (int l = 0; l < 4; ++l) {
            float v = o[ri][l];
            bf16 hv = (bf16)v;
            hi[l] = hv;
            lo[l] = (bf16)(v - (float)hv);
        }
        *(bf16x4*)(dst)        = hi;
        *(bf16x4*)(dst + 512)  = hi;
        *(bf16x4*)(dst + 1024) = lo;
    }
}

// ---------------------------------------------------------------------------
extern "C" void kernel_launch(void* const* d_in, const int* in_sizes, int n_in,
                              void* d_out, int out_size, void* d_ws, size_t ws_size,
                              hipStream_t stream)
{
    (void)in_sizes; (void)n_in; (void)out_size; (void)ws_size;

    const float* x  = (const float*)d_in[0];
    const float* Wq = (const float*)d_in[1];
    const float* Wk = (const float*)d_in[2];
    const float* Wv = (const float*)d_in[3];
    const float* Wo = (const float*)d_in[4];
    const float* bq = (const float*)d_in[5];
    const float* bk = (const float*)d_in[6];
    const float* bv = (const float*)d_in[7];
    const float* bo = (const float*)d_in[8];
    float* out = (float*)d_out;

    // workspace: qb 8M | kb 8M | vb 8M | st 8M | xa 12M | wa 12M
    char* ws = (char*)d_ws;
    float* qb = (float*)(ws);
    float* kb = (float*)(ws + (size_t)8  * 1024 * 1024);
    float* vb = (float*)(ws + (size_t)16 * 1024 * 1024);
    float* st = (float*)(ws + (size_t)24 * 1024 * 1024);
    bf16*  xa = (bf16*) (ws + (size_t)32 * 1024 * 1024);   // reused as attn aug
    bf16*  wa = (bf16*) (ws + (size_t)44 * 1024 * 1024);

    dim3 blk(256);

    split_x<<<dim3(2048), blk, 0, stream>>>(x, xa);
    split_w<<<dim3(256, 4), blk, 0, stream>>>(Wq, Wk, Wv, Wo, wa);

    // fused q,k,v projections
    mm_aug<0><<<dim3(64, 4, 3), blk, 0, stream>>>(xa, wa, bq, bk, bv, qb);

    chunk_state<<<dim3(32, NCHUNK), blk, 0, stream>>>(kb, vb, st);
    prefix_scan<<<dim3(32, 16), blk, 0, stream>>>(st);
    attn_chunk<<<dim3(32, NCHUNK), blk, 0, stream>>>(qb, kb, vb, st, xa);

    // out projection: full K, plain stores + bias
    mm_aug<1><<<dim3(64, 8), blk, 0, stream>>>(xa, wa + (size_t)3 * WMAT, bo, nullptr, nullptr, out);
}